// Round 2
// baseline (303.071 us; speedup 1.0000x reference)
//
#include <hip/hip_runtime.h>
#include <math.h>

#define O_ 3
#define P_ 128
#define G_ 64
#define N_ 20000
#define H_ 512
#define D_ 128
#define M_ (O_*P_)          // 384 anchors
#define R_ 4                // rows per block in fused kernel

static constexpr float TEMP_INV = 10.0f;   // 1/0.1
static constexpr float EPS_ = 1e-12f;

// ---------------------------------------------------------------------------
// KA: fully fused per-row pipeline:
//   gather+mean (protos, LDS) -> GEMM1+ReLU (h, LDS) -> GEMM2 -> l2-norm -> z
// 96 blocks = 3 omics x 32 row-groups of R_=4 rows; 512 threads.
// W1 traffic: 1 MB/block (96 MB total); W2 traffic: 256 KB/block (24 MB total,
// 4x less than the unfused version); no hbuf/protos global round-trips.
// ---------------------------------------------------------------------------
__global__ __launch_bounds__(512) void k_fused(const float* __restrict__ emb,
                                               const int* __restrict__ idx,
                                               const float* __restrict__ W1,
                                               const float* __restrict__ b1,
                                               const float* __restrict__ W2,
                                               const float* __restrict__ b2,
                                               float* __restrict__ z) {
    const int blk = blockIdx.x;               // o*32 + pg
    const int o = blk >> 5, pg = blk & 31;
    const int p0 = pg * R_;
    const int t = threadIdx.x;                // 0..511

    __shared__ int   sIdx[R_][G_];            // 1 KB
    __shared__ float sPr[R_][H_];             // 8 KB  (protos rows)
    __shared__ float sH[R_][H_];              // 8 KB  (hidden rows)
    __shared__ float red[8];                  // norm partials (4 rows x 2 waves)

    if (t < R_ * G_)
        sIdx[t >> 6][t & 63] = idx[(o * P_ + p0 + (t >> 6)) * G_ + (t & 63)];
    __syncthreads();

    // ---- phase 1: gather + mean -> sPr ----
    {
        const int r = t >> 7, c4 = t & 127;
        const float* base = emb + (size_t)o * N_ * H_ + (size_t)c4 * 4;
        float4 acc = make_float4(0.f, 0.f, 0.f, 0.f);
        #pragma unroll 16
        for (int g = 0; g < G_; ++g) {
            const float4 v = *(const float4*)(base + (size_t)((unsigned)sIdx[r][g]) * H_);
            acc.x += v.x; acc.y += v.y; acc.z += v.z; acc.w += v.w;
        }
        const float s = 1.0f / (float)G_;
        ((float4*)sPr[r])[c4] = make_float4(acc.x * s, acc.y * s, acc.z * s, acc.w * s);
    }
    __syncthreads();

    // ---- phase 2: GEMM1 (4 rows x 512 k) + ReLU -> sH ----
    {
        const int k = t;
        const float bias = b1[o * H_ + k];
        float acc0 = bias, acc1 = bias, acc2 = bias, acc3 = bias;
        const float* w1 = W1 + (size_t)o * H_ * H_ + k;
        const float4* p0v = (const float4*)sPr[0];
        const float4* p1v = (const float4*)sPr[1];
        const float4* p2v = (const float4*)sPr[2];
        const float4* p3v = (const float4*)sPr[3];

        #pragma unroll 4
        for (int h4 = 0; h4 < H_ / 4; ++h4) {
            const float4 a0 = p0v[h4];
            const float4 a1 = p1v[h4];
            const float4 a2 = p2v[h4];
            const float4 a3 = p3v[h4];
            const float w_0 = w1[(size_t)(h4 * 4 + 0) * H_];
            const float w_1 = w1[(size_t)(h4 * 4 + 1) * H_];
            const float w_2 = w1[(size_t)(h4 * 4 + 2) * H_];
            const float w_3 = w1[(size_t)(h4 * 4 + 3) * H_];
            acc0 = fmaf(a0.x, w_0, fmaf(a0.y, w_1, fmaf(a0.z, w_2, fmaf(a0.w, w_3, acc0))));
            acc1 = fmaf(a1.x, w_0, fmaf(a1.y, w_1, fmaf(a1.z, w_2, fmaf(a1.w, w_3, acc1))));
            acc2 = fmaf(a2.x, w_0, fmaf(a2.y, w_1, fmaf(a2.z, w_2, fmaf(a2.w, w_3, acc2))));
            acc3 = fmaf(a3.x, w_0, fmaf(a3.y, w_1, fmaf(a3.z, w_2, fmaf(a3.w, w_3, acc3))));
        }
        sH[0][k] = fmaxf(acc0, 0.f);
        sH[1][k] = fmaxf(acc1, 0.f);
        sH[2][k] = fmaxf(acc2, 0.f);
        sH[3][k] = fmaxf(acc3, 0.f);
    }
    __syncthreads();

    // ---- phase 3: GEMM2 (4 rows x 128 d) + l2-norm -> z ----
    {
        const int d = t & 127, rr = t >> 7;   // thread = (row rr, output d)
        const float* hr = sH[rr];
        const float* w2 = W2 + (size_t)o * H_ * D_ + d;
        float acc = b2[o * D_ + d];
        #pragma unroll 8
        for (int kk = 0; kk < H_; ++kk)
            acc = fmaf(hr[kk], w2[(size_t)kk * D_], acc);

        // row norm: threads [rr*128, rr*128+128) = 2 waves
        float s = acc * acc;
        #pragma unroll
        for (int off = 32; off > 0; off >>= 1) s += __shfl_down(s, off, 64);
        const int lane = t & 63, widg = t >> 6;   // global wave id 0..7
        if (lane == 0) red[widg] = s;
        __syncthreads();
        const float nrm = sqrtf(red[rr * 2] + red[rr * 2 + 1]);
        const float inv = 1.0f / (nrm + EPS_);
        z[(size_t)((p0 + rr) * O_ + o) * D_ + d] = acc * inv;
    }
}

// ---------------------------------------------------------------------------
// KC: supervised-contrastive loss. One block per anchor i (384 blocks, 256 thr
// = 4 waves). Thread t handles j = t, plus j = t+256 if t < 128.
// ---------------------------------------------------------------------------
__global__ __launch_bounds__(256) void k_loss(const float* __restrict__ z,
                                              float* __restrict__ out) {
    const int i = blockIdx.x;            // 0..383
    const int t = threadIdx.x;
    __shared__ float zi[D_];
    if (t < D_) zi[t] = z[(size_t)i * D_ + t];
    __syncthreads();
    const int pi = i / 3;                // pathway label of anchor
    float denom = 0.f, pos = 0.f;
    const float4* zi4 = (const float4*)zi;
    #pragma unroll
    for (int jj = 0; jj < 2; ++jj) {
        const int j = t + jj * 256;
        if (j < M_) {
            const float4* zj = (const float4*)(z + (size_t)j * D_);
            float dot = 0.f;
            #pragma unroll 8
            for (int q = 0; q < D_ / 4; ++q) {
                const float4 a = zi4[q];
                const float4 bb = zj[q];
                dot = fmaf(a.x, bb.x, fmaf(a.y, bb.y, fmaf(a.z, bb.z, fmaf(a.w, bb.w, dot))));
            }
            if (j != i) {
                const float e = __expf(dot * TEMP_INV);
                denom += e;
                if (j / 3 == pi) pos += e;
            }
        }
    }
    #pragma unroll
    for (int off = 32; off > 0; off >>= 1) {
        denom += __shfl_down(denom, off, 64);
        pos   += __shfl_down(pos,   off, 64);
    }
    __shared__ float rd[4], rp[4];
    const int lane = t & 63, wid = t >> 6;
    if (lane == 0) { rd[wid] = denom; rp[wid] = pos; }
    __syncthreads();
    if (t == 0) {
        const float dn = rd[0] + rd[1] + rd[2] + rd[3] + EPS_;
        const float ps = rp[0] + rp[1] + rp[2] + rp[3] + EPS_;
        const float loss_i = logf(dn) - logf(ps);   // = -log(pos/denom)
        atomicAdd(out, loss_i * (1.0f / (float)M_));
    }
}

// ---------------------------------------------------------------------------
extern "C" void kernel_launch(void* const* d_in, const int* in_sizes, int n_in,
                              void* d_out, int out_size, void* d_ws, size_t ws_size,
                              hipStream_t stream) {
    const float* emb = (const float*)d_in[0];   // [3,20000,512]
    const float* W1  = (const float*)d_in[1];   // [3,512,512]
    const float* b1  = (const float*)d_in[2];   // [3,512]
    const float* W2  = (const float*)d_in[3];   // [3,512,128]
    const float* b2  = (const float*)d_in[4];   // [3,128]
    const int*   idx = (const int*)d_in[5];     // [3,128,64]

    float* zbuf = (float*)d_ws;                 // 384*128 = 49152 floats

    // d_out is re-poisoned to 0xAA before every replay: zero it in-graph.
    hipMemsetAsync(d_out, 0, sizeof(float), stream);

    k_fused<<<dim3(96), dim3(512), 0, stream>>>(emb, idx, W1, b1, W2, b2, zbuf);
    k_loss <<<dim3(M_), dim3(256), 0, stream>>>(zbuf, (float*)d_out);
}

// Round 3
// 223.310 us; speedup vs baseline: 1.3572x; 1.3572x over previous
//
#include <hip/hip_runtime.h>
#include <math.h>

#define O_ 3
#define P_ 128
#define G_ 64
#define N_ 20000
#define H_ 512
#define D_ 128
#define M_ (O_*P_)          // 384 anchors

static constexpr float TEMP_INV = 10.0f;   // 1/0.1
static constexpr float EPS_ = 1e-12f;

// ---------------------------------------------------------------------------
// K1: protos[b][h] = mean_g emb[o][idx[b][g]][h].  384 blocks x 512 threads.
// Thread = (g-quarter q, float4 col c4). Each sums 16 gathered rows (fully
// unrolled -> 16 independent 16B loads in flight), then LDS combine over q.
// 12 waves/CU during the latency-critical gather.
// ---------------------------------------------------------------------------
__global__ __launch_bounds__(512) void k_protos(const float* __restrict__ emb,
                                                const int* __restrict__ idx,
                                                float* __restrict__ protos) {
    const int b = blockIdx.x;            // o*128 + p
    const int o = b >> 7;
    const int t = threadIdx.x;
    const int q = t >> 7, c4 = t & 127;

    __shared__ int sIdx[G_];
    __shared__ float4 sRed[4][128];      // 8 KB

    if (t < G_) sIdx[t] = idx[b * G_ + t];
    __syncthreads();

    const float* base = emb + (size_t)o * N_ * H_ + (size_t)c4 * 4;
    float4 acc = make_float4(0.f, 0.f, 0.f, 0.f);
    #pragma unroll
    for (int g = 0; g < 16; ++g) {
        const float4 v = *(const float4*)(base + (size_t)((unsigned)sIdx[q * 16 + g]) * H_);
        acc.x += v.x; acc.y += v.y; acc.z += v.z; acc.w += v.w;
    }
    sRed[q][c4] = acc;
    __syncthreads();

    if (q == 0) {
        const float4 a0 = sRed[0][c4], a1 = sRed[1][c4];
        const float4 a2 = sRed[2][c4], a3 = sRed[3][c4];
        const float s = 1.0f / (float)G_;
        float4 r;
        r.x = (a0.x + a1.x + a2.x + a3.x) * s;
        r.y = (a0.y + a1.y + a2.y + a3.y) * s;
        r.z = (a0.z + a1.z + a2.z + a3.z) * s;
        r.w = (a0.w + a1.w + a2.w + a3.w) * s;
        ((float4*)(protos + (size_t)b * H_))[c4] = r;
    }
}

// ---------------------------------------------------------------------------
// K2: hbuf = relu(protos @ W1 + b1).  384 blocks (one per (o,p)) x 512 threads.
// Thread = (k-split ks 0..3 over h, output quad kq -> cols 4kq..4kq+3).
// W1 read as float4 (1 KB/wave contiguous); proto row broadcast from LDS.
// 4 independent acc chains of 128 FMAs; LDS reduce over ks.
// ---------------------------------------------------------------------------
__global__ __launch_bounds__(512) void k_gemm1(const float* __restrict__ protos,
                                               const float* __restrict__ W1,
                                               const float* __restrict__ b1,
                                               float* __restrict__ hbuf) {
    const int b = blockIdx.x;            // o*128 + p
    const int o = b >> 7;
    const int t = threadIdx.x;
    const int ks = t >> 7, kq = t & 127;

    __shared__ float sP[H_];             // 2 KB
    __shared__ float4 sPart[4][128];     // 8 KB

    sP[t] = protos[(size_t)b * H_ + t];
    __syncthreads();

    const float4* w1 = (const float4*)(W1 + (size_t)o * H_ * H_) + kq;  // row h at w1[h*128]
    float4 acc = make_float4(0.f, 0.f, 0.f, 0.f);
    const int h0 = ks * 128;
    #pragma unroll 8
    for (int h = 0; h < 128; ++h) {
        const float a = sP[h0 + h];
        const float4 w = w1[(size_t)(h0 + h) * 128];
        acc.x = fmaf(a, w.x, acc.x);
        acc.y = fmaf(a, w.y, acc.y);
        acc.z = fmaf(a, w.z, acc.z);
        acc.w = fmaf(a, w.w, acc.w);
    }
    sPart[ks][kq] = acc;
    __syncthreads();

    if (ks == 0) {
        const float4 r0 = sPart[0][kq], r1 = sPart[1][kq];
        const float4 r2 = sPart[2][kq], r3 = sPart[3][kq];
        const float4 bb = ((const float4*)(b1 + (size_t)o * H_))[kq];
        float4 r;
        r.x = fmaxf(r0.x + r1.x + r2.x + r3.x + bb.x, 0.f);
        r.y = fmaxf(r0.y + r1.y + r2.y + r3.y + bb.y, 0.f);
        r.z = fmaxf(r0.z + r1.z + r2.z + r3.z + bb.z, 0.f);
        r.w = fmaxf(r0.w + r1.w + r2.w + r3.w + bb.w, 0.f);
        ((float4*)(hbuf + (size_t)b * H_))[kq] = r;
    }
}

// ---------------------------------------------------------------------------
// K3: z-row = l2norm(hbuf @ W2 + b2); store at anchor m = p*3 + o.
// 384 blocks x 512 threads. Thread = (k-split ks 0..15 over h, quad dq 0..31).
// ---------------------------------------------------------------------------
__global__ __launch_bounds__(512) void k_gemm2_norm(const float* __restrict__ hbuf,
                                                    const float* __restrict__ W2,
                                                    const float* __restrict__ b2,
                                                    float* __restrict__ z) {
    const int b = blockIdx.x;            // o*128 + p
    const int o = b >> 7, p = b & 127;
    const int t = threadIdx.x;
    const int ks = t >> 5, dq = t & 31;

    __shared__ float sH[H_];             // 2 KB
    __shared__ float4 sPart[16][32];     // 8 KB
    __shared__ float sZ[D_];             // 0.5 KB
    __shared__ float sNr[2];

    sH[t] = hbuf[(size_t)b * H_ + t];
    __syncthreads();

    const float4* w2 = (const float4*)(W2 + (size_t)o * H_ * D_) + dq;  // row h at w2[h*32]
    float4 acc = make_float4(0.f, 0.f, 0.f, 0.f);
    const int h0 = ks * 32;
    #pragma unroll 8
    for (int h = 0; h < 32; ++h) {
        const float a = sH[h0 + h];
        const float4 w = w2[(size_t)(h0 + h) * 32];
        acc.x = fmaf(a, w.x, acc.x);
        acc.y = fmaf(a, w.y, acc.y);
        acc.z = fmaf(a, w.z, acc.z);
        acc.w = fmaf(a, w.w, acc.w);
    }
    sPart[ks][dq] = acc;
    __syncthreads();

    if (t < 32) {
        float4 s = make_float4(0.f, 0.f, 0.f, 0.f);
        #pragma unroll
        for (int j = 0; j < 16; ++j) {
            const float4 v = sPart[j][t];
            s.x += v.x; s.y += v.y; s.z += v.z; s.w += v.w;
        }
        const float4 bb = ((const float4*)(b2 + (size_t)o * D_))[t];
        s.x += bb.x; s.y += bb.y; s.z += bb.z; s.w += bb.w;
        ((float4*)sZ)[t] = s;
    }
    __syncthreads();

    if (t < D_) {                         // waves 0 and 1, fully active
        const float v = sZ[t];
        float s = v * v;
        #pragma unroll
        for (int off = 32; off > 0; off >>= 1) s += __shfl_down(s, off, 64);
        if ((t & 63) == 0) sNr[t >> 6] = s;
    }
    __syncthreads();
    if (t < D_) {
        const float inv = 1.0f / (sqrtf(sNr[0] + sNr[1]) + EPS_);
        z[(size_t)(p * O_ + o) * D_ + t] = sZ[t] * inv;
    }
}

// ---------------------------------------------------------------------------
// K4: supervised-contrastive loss. One block per anchor i (384 blocks, 256 thr
// = 4 waves). Thread t handles j = t, plus j = t+256 if t < 128.
// ---------------------------------------------------------------------------
__global__ __launch_bounds__(256) void k_loss(const float* __restrict__ z,
                                              float* __restrict__ out) {
    const int i = blockIdx.x;            // 0..383
    const int t = threadIdx.x;
    __shared__ float zi[D_];
    if (t < D_) zi[t] = z[(size_t)i * D_ + t];
    __syncthreads();
    const int pi = i / 3;                // pathway label of anchor
    float denom = 0.f, pos = 0.f;
    const float4* zi4 = (const float4*)zi;
    #pragma unroll
    for (int jj = 0; jj < 2; ++jj) {
        const int j = t + jj * 256;
        if (j < M_) {
            const float4* zj = (const float4*)(z + (size_t)j * D_);
            float dot = 0.f;
            #pragma unroll 8
            for (int q = 0; q < D_ / 4; ++q) {
                const float4 a = zi4[q];
                const float4 bb = zj[q];
                dot = fmaf(a.x, bb.x, fmaf(a.y, bb.y, fmaf(a.z, bb.z, fmaf(a.w, bb.w, dot))));
            }
            if (j != i) {
                const float e = __expf(dot * TEMP_INV);
                denom += e;
                if (j / 3 == pi) pos += e;
            }
        }
    }
    #pragma unroll
    for (int off = 32; off > 0; off >>= 1) {
        denom += __shfl_down(denom, off, 64);
        pos   += __shfl_down(pos,   off, 64);
    }
    __shared__ float rd[4], rp[4];
    const int lane = t & 63, wid = t >> 6;
    if (lane == 0) { rd[wid] = denom; rp[wid] = pos; }
    __syncthreads();
    if (t == 0) {
        const float dn = rd[0] + rd[1] + rd[2] + rd[3] + EPS_;
        const float ps = rp[0] + rp[1] + rp[2] + rp[3] + EPS_;
        const float loss_i = logf(dn) - logf(ps);   // = -log(pos/denom)
        atomicAdd(out, loss_i * (1.0f / (float)M_));
    }
}

// ---------------------------------------------------------------------------
extern "C" void kernel_launch(void* const* d_in, const int* in_sizes, int n_in,
                              void* d_out, int out_size, void* d_ws, size_t ws_size,
                              hipStream_t stream) {
    const float* emb = (const float*)d_in[0];   // [3,20000,512]
    const float* W1  = (const float*)d_in[1];   // [3,512,512]
    const float* b1  = (const float*)d_in[2];   // [3,512]
    const float* W2  = (const float*)d_in[3];   // [3,512,128]
    const float* b2  = (const float*)d_in[4];   // [3,128]
    const int*   idx = (const int*)d_in[5];     // [3,128,64]

    float* ws     = (float*)d_ws;
    float* protos = ws;                         // 384*512 floats
    float* hbuf   = ws + 196608;                // 384*512 floats
    float* zbuf   = ws + 393216;                // 384*128 floats

    // d_out is re-poisoned to 0xAA before every replay: zero it in-graph.
    hipMemsetAsync(d_out, 0, sizeof(float), stream);

    k_protos    <<<dim3(M_), dim3(512), 0, stream>>>(emb, idx, protos);
    k_gemm1     <<<dim3(M_), dim3(512), 0, stream>>>(protos, W1, b1, hbuf);
    k_gemm2_norm<<<dim3(M_), dim3(512), 0, stream>>>(hbuf, W2, b2, zbuf);
    k_loss      <<<dim3(M_), dim3(256), 0, stream>>>(zbuf, (float*)d_out);
}

// Round 4
// 219.711 us; speedup vs baseline: 1.3794x; 1.0164x over previous
//
#include <hip/hip_runtime.h>
#include <math.h>

#define O_ 3
#define P_ 128
#define G_ 64
#define N_ 20000
#define H_ 512
#define D_ 128
#define M_ (O_*P_)          // 384 anchors

static constexpr float TEMP_INV = 10.0f;   // 1/0.1
static constexpr float EPS_ = 1e-12f;

// ---------------------------------------------------------------------------
// K1: protos[b][h] = mean_g emb[o][idx[b][g]][h].  384 blocks x 512 threads.
// Thread = (g-quarter q, float4 col c4). Each sums 16 gathered rows (fully
// unrolled -> 16 independent 16B loads in flight), then LDS combine over q.
// ---------------------------------------------------------------------------
__global__ __launch_bounds__(512) void k_protos(const float* __restrict__ emb,
                                                const int* __restrict__ idx,
                                                float* __restrict__ protos) {
    const int b = blockIdx.x;            // o*128 + p
    const int o = b >> 7;
    const int t = threadIdx.x;
    const int q = t >> 7, c4 = t & 127;

    __shared__ int sIdx[G_];
    __shared__ float4 sRed[4][128];      // 8 KB

    if (t < G_) sIdx[t] = idx[b * G_ + t];
    __syncthreads();

    const float* base = emb + (size_t)o * N_ * H_ + (size_t)c4 * 4;
    float4 acc = make_float4(0.f, 0.f, 0.f, 0.f);
    #pragma unroll
    for (int g = 0; g < 16; ++g) {
        const float4 v = *(const float4*)(base + (size_t)((unsigned)sIdx[q * 16 + g]) * H_);
        acc.x += v.x; acc.y += v.y; acc.z += v.z; acc.w += v.w;
    }
    sRed[q][c4] = acc;
    __syncthreads();

    if (q == 0) {
        const float4 a0 = sRed[0][c4], a1 = sRed[1][c4];
        const float4 a2 = sRed[2][c4], a3 = sRed[3][c4];
        const float s = 1.0f / (float)G_;
        float4 r;
        r.x = (a0.x + a1.x + a2.x + a3.x) * s;
        r.y = (a0.y + a1.y + a2.y + a3.y) * s;
        r.z = (a0.z + a1.z + a2.z + a3.z) * s;
        r.w = (a0.w + a1.w + a2.w + a3.w) * s;
        ((float4*)(protos + (size_t)b * H_))[c4] = r;
    }
}

// ---------------------------------------------------------------------------
// K2: hbuf = relu(protos @ W1 + b1).
// 384 blocks = o(3) x pg(16: 8 rows each) x ks(8: 64-col k-slice).
// W1 traffic: 128 KB/block -> 48 MB total (8x less than full-W1-per-block).
// 8 proto rows staged in LDS with +4 float row pad (stride 516): the 4
// distinct rows read per wave land on banks {4r mod 32} -> conflict-free,
// and row starts stay 16B-aligned for float4 staging.
// Thread t = (hs = t>>7: h-split 0..3, r = (t>>4)&7: row, q4 = t&15: col quad).
// ---------------------------------------------------------------------------
#define PRSTR 516            // padded proto row stride in floats (516*4B, 16B-aligned)
__global__ __launch_bounds__(512) void k_gemm1(const float* __restrict__ protos,
                                               const float* __restrict__ W1,
                                               const float* __restrict__ b1,
                                               float* __restrict__ hbuf) {
    const int blk = blockIdx.x;          // o*128 + pg*8 + ks
    const int o = blk >> 7;
    const int rem = blk & 127;
    const int pg = rem >> 3, ks = rem & 7;
    const int p0 = pg * 8, k0 = ks * 64;
    const int t = threadIdx.x;
    const int hs = t >> 7, r = (t >> 4) & 7, q4 = t & 15;

    __shared__ float sPr[8 * PRSTR];     // 16.1 KB (8 padded proto rows)
    __shared__ float4 sPart[4][8][16];   // 8 KB

    // stage 8 proto rows (float4, coalesced)
    {
        const float4* src = (const float4*)(protos + (size_t)(o * P_ + p0) * H_);
        #pragma unroll
        for (int i = 0; i < 2; ++i) {
            const int fidx = i * 512 + t;          // 0..1023
            const int rr = fidx >> 7, c4 = fidx & 127;
            ((float4*)sPr)[rr * (PRSTR / 4) + c4] = src[rr * 128 + c4];
        }
    }
    __syncthreads();

    const float4* w1 = (const float4*)(W1 + (size_t)o * H_ * H_) + (k0 >> 2) + q4;
    const float* pr = sPr + r * PRSTR + hs * 128;
    float4 acc = make_float4(0.f, 0.f, 0.f, 0.f);
    #pragma unroll 8
    for (int h = 0; h < 128; ++h) {
        const float a = pr[h];
        const float4 w = w1[(size_t)(hs * 128 + h) * 128];
        acc.x = fmaf(a, w.x, acc.x);
        acc.y = fmaf(a, w.y, acc.y);
        acc.z = fmaf(a, w.z, acc.z);
        acc.w = fmaf(a, w.w, acc.w);
    }
    sPart[hs][r][q4] = acc;
    __syncthreads();

    if (hs == 0) {                        // t < 128: r = (t>>4)&7, q4 = t&15
        const float4 r0 = sPart[0][r][q4], r1 = sPart[1][r][q4];
        const float4 r2 = sPart[2][r][q4], r3 = sPart[3][r][q4];
        const float4 bb = ((const float4*)(b1 + (size_t)o * H_ + k0))[q4];
        float4 out;
        out.x = fmaxf(r0.x + r1.x + r2.x + r3.x + bb.x, 0.f);
        out.y = fmaxf(r0.y + r1.y + r2.y + r3.y + bb.y, 0.f);
        out.z = fmaxf(r0.z + r1.z + r2.z + r3.z + bb.z, 0.f);
        out.w = fmaxf(r0.w + r1.w + r2.w + r3.w + bb.w, 0.f);
        ((float4*)(hbuf + (size_t)(o * P_ + p0 + r) * H_ + k0))[q4] = out;
    }
}

// ---------------------------------------------------------------------------
// K3: z-row = l2norm(hbuf @ W2 + b2); store at anchor m = p*3 + o.
// 384 blocks x 512 threads. Thread = (k-split ks 0..15 over h, quad dq 0..31).
// ---------------------------------------------------------------------------
__global__ __launch_bounds__(512) void k_gemm2_norm(const float* __restrict__ hbuf,
                                                    const float* __restrict__ W2,
                                                    const float* __restrict__ b2,
                                                    float* __restrict__ z) {
    const int b = blockIdx.x;            // o*128 + p
    const int o = b >> 7, p = b & 127;
    const int t = threadIdx.x;
    const int ks = t >> 5, dq = t & 31;

    __shared__ float sH[H_];             // 2 KB
    __shared__ float4 sPart[16][32];     // 8 KB
    __shared__ float sZ[D_];             // 0.5 KB
    __shared__ float sNr[2];

    sH[t] = hbuf[(size_t)b * H_ + t];
    __syncthreads();

    const float4* w2 = (const float4*)(W2 + (size_t)o * H_ * D_) + dq;  // row h at w2[h*32]
    float4 acc = make_float4(0.f, 0.f, 0.f, 0.f);
    const int h0 = ks * 32;
    #pragma unroll 8
    for (int h = 0; h < 32; ++h) {
        const float a = sH[h0 + h];
        const float4 w = w2[(size_t)(h0 + h) * 32];
        acc.x = fmaf(a, w.x, acc.x);
        acc.y = fmaf(a, w.y, acc.y);
        acc.z = fmaf(a, w.z, acc.z);
        acc.w = fmaf(a, w.w, acc.w);
    }
    sPart[ks][dq] = acc;
    __syncthreads();

    if (t < 32) {
        float4 s = make_float4(0.f, 0.f, 0.f, 0.f);
        #pragma unroll
        for (int j = 0; j < 16; ++j) {
            const float4 v = sPart[j][t];
            s.x += v.x; s.y += v.y; s.z += v.z; s.w += v.w;
        }
        const float4 bb = ((const float4*)(b2 + (size_t)o * D_))[t];
        s.x += bb.x; s.y += bb.y; s.z += bb.z; s.w += bb.w;
        ((float4*)sZ)[t] = s;
    }
    __syncthreads();

    if (t < D_) {                         // waves 0 and 1, fully active
        const float v = sZ[t];
        float s = v * v;
        #pragma unroll
        for (int off = 32; off > 0; off >>= 1) s += __shfl_down(s, off, 64);
        if ((t & 63) == 0) sNr[t >> 6] = s;
    }
    __syncthreads();
    if (t < D_) {
        const float inv = 1.0f / (sqrtf(sNr[0] + sNr[1]) + EPS_);
        z[(size_t)(p * O_ + o) * D_ + t] = sZ[t] * inv;
    }
}

// ---------------------------------------------------------------------------
// K4: supervised-contrastive loss. One block per anchor i (384 blocks, 256 thr
// = 4 waves). Thread t handles j = t, plus j = t+256 if t < 128.
// ---------------------------------------------------------------------------
__global__ __launch_bounds__(256) void k_loss(const float* __restrict__ z,
                                              float* __restrict__ out) {
    const int i = blockIdx.x;            // 0..383
    const int t = threadIdx.x;
    __shared__ float zi[D_];
    if (t < D_) zi[t] = z[(size_t)i * D_ + t];
    __syncthreads();
    const int pi = i / 3;                // pathway label of anchor
    float denom = 0.f, pos = 0.f;
    const float4* zi4 = (const float4*)zi;
    #pragma unroll
    for (int jj = 0; jj < 2; ++jj) {
        const int j = t + jj * 256;
        if (j < M_) {
            const float4* zj = (const float4*)(z + (size_t)j * D_);
            float dot = 0.f;
            #pragma unroll 8
            for (int q = 0; q < D_ / 4; ++q) {
                const float4 a = zi4[q];
                const float4 bb = zj[q];
                dot = fmaf(a.x, bb.x, fmaf(a.y, bb.y, fmaf(a.z, bb.z, fmaf(a.w, bb.w, dot))));
            }
            if (j != i) {
                const float e = __expf(dot * TEMP_INV);
                denom += e;
                if (j / 3 == pi) pos += e;
            }
        }
    }
    #pragma unroll
    for (int off = 32; off > 0; off >>= 1) {
        denom += __shfl_down(denom, off, 64);
        pos   += __shfl_down(pos,   off, 64);
    }
    __shared__ float rd[4], rp[4];
    const int lane = t & 63, wid = t >> 6;
    if (lane == 0) { rd[wid] = denom; rp[wid] = pos; }
    __syncthreads();
    if (t == 0) {
        const float dn = rd[0] + rd[1] + rd[2] + rd[3] + EPS_;
        const float ps = rp[0] + rp[1] + rp[2] + rp[3] + EPS_;
        const float loss_i = logf(dn) - logf(ps);   // = -log(pos/denom)
        atomicAdd(out, loss_i * (1.0f / (float)M_));
    }
}

// ---------------------------------------------------------------------------
extern "C" void kernel_launch(void* const* d_in, const int* in_sizes, int n_in,
                              void* d_out, int out_size, void* d_ws, size_t ws_size,
                              hipStream_t stream) {
    const float* emb = (const float*)d_in[0];   // [3,20000,512]
    const float* W1  = (const float*)d_in[1];   // [3,512,512]
    const float* b1  = (const float*)d_in[2];   // [3,512]
    const float* W2  = (const float*)d_in[3];   // [3,512,128]
    const float* b2  = (const float*)d_in[4];   // [3,128]
    const int*   idx = (const int*)d_in[5];     // [3,128,64]

    float* ws     = (float*)d_ws;
    float* protos = ws;                         // 384*512 floats
    float* hbuf   = ws + 196608;                // 384*512 floats
    float* zbuf   = ws + 393216;                // 384*128 floats

    // d_out is re-poisoned to 0xAA before every replay: zero it in-graph.
    hipMemsetAsync(d_out, 0, sizeof(float), stream);

    k_protos    <<<dim3(M_), dim3(512), 0, stream>>>(emb, idx, protos);
    k_gemm1     <<<dim3(M_), dim3(512), 0, stream>>>(protos, W1, b1, hbuf);
    k_gemm2_norm<<<dim3(M_), dim3(512), 0, stream>>>(hbuf, W2, b2, zbuf);
    k_loss      <<<dim3(M_), dim3(256), 0, stream>>>(zbuf, (float*)d_out);
}